// Round 7
// baseline (273.047 us; speedup 1.0000x reference)
//
#include <hip/hip_runtime.h>
#include <stdint.h>

#define B 64
#define N 784
#define C 512
#define M 256

typedef unsigned long long u64;
typedef unsigned short u16;
typedef __attribute__((ext_vector_type(8))) short short8;
typedef __attribute__((ext_vector_type(4))) float f32x4;

static __device__ __forceinline__ u64 umin64(u64 a, u64 b) { return a < b ? a : b; }

static __device__ __forceinline__ u16 f2bf(float x) {   // RNE fp32 -> bf16
    unsigned u = __float_as_uint(x);
    return (u16)((u + 0x7FFFu + ((u >> 16) & 1u)) >> 16);
}
static __device__ __forceinline__ float b2f(u16 v) {
    return __uint_as_float((unsigned)v << 16);
}

static __device__ __forceinline__ void gload_lds16(const u16* g, u16* l) {
    __builtin_amdgcn_global_load_lds((const __attribute__((address_space(1))) void*)g,
                                     (__attribute__((address_space(3))) void*)l, 16, 0, 0);
}

// ---------------------------------------------------------------------------
// fused fp32->bf16 convert + row |x|^2 norms. One wave per row (512 floats).
// ---------------------------------------------------------------------------
__global__ __launch_bounds__(256) void convnorm_kernel(
    const float* __restrict__ m1, const float* __restrict__ m2,
    u16* __restrict__ abf, u16* __restrict__ bbf, float* __restrict__ nrm) {
    int w = blockIdx.x * 4 + (threadIdx.x >> 6);
    int lane = threadIdx.x & 63;
    if (w >= 2 * B * N) return;
    const float* src = (w < B * N) ? m1 : m2;
    u16* dst = (w < B * N) ? abf : bbf;
    int row = (w < B * N) ? w : w - B * N;
    const float4* p = (const float4*)(src + (size_t)row * C);
    u64* q = (u64*)(dst + (size_t)row * C);
    float s = 0.f;
#pragma unroll
    for (int i = 0; i < 2; ++i) {
        int idx = lane + i * 64;
        float4 v = p[idx];
        s += v.x * v.x + v.y * v.y + v.z * v.z + v.w * v.w;
        q[idx] = (u64)f2bf(v.x) | ((u64)f2bf(v.y) << 16) |
                 ((u64)f2bf(v.z) << 32) | ((u64)f2bf(v.w) << 48);
    }
#pragma unroll
    for (int off = 32; off > 0; off >>= 1) s += __shfl_down(s, off, 64);
    if (lane == 0) nrm[w] = s;
}

// ---------------------------------------------------------------------------
// MFMA feature-distance, m97 structure at 4 blocks/CU:
//  single 32KB staging buffer (stage -> sync -> compute -> sync); the per-
//  block drain stall is hidden by 3 other co-resident blocks' compute (m114
//  implicit overlap — this, not dbuf, is what m97's 874 TF used).
//  Epilogue u64 min-table ALIASES the staging LDS (union, 34.8KB total).
// 128x128 tile, BK=64, 4 waves (2x2, each 64x64). LDS linear for
// global_load_lds; source chunk pre-XOR-swizzled, ds_read applies same XOR.
// ---------------------------------------------------------------------------
__global__ __launch_bounds__(256, 4) void feat_mfma_kernel(
    const u16* __restrict__ abf, const u16* __restrict__ bbf,
    const float* __restrict__ nrm, u64* __restrict__ rowkey) {
    // decode: id = ((b>>3)*49 + tile)*8 + (b&7)  (batch->XCD affinity)
    int id = blockIdx.x;
    int xcd = id & 7;
    int q = id >> 3;
    int hi = q / 49, t49 = q - hi * 49;
    int b = hi * 8 + xcd;
    int tn = t49 / 7, tm = t49 - tn * 7;

    const int t = threadIdx.x;
    const int lane = t & 63, wv = t >> 6;
    const int wr = wv >> 1, wc = wv & 1;

    // union: staging (Als 16KB + Bls 16KB) / epilogue red[128][33] u64 (33.8KB)
    __shared__ __align__(16) unsigned char RAW[33792];
    u16* Als = (u16*)RAW;
    u16* Bls = (u16*)(RAW + 16384);
    __shared__ float sNa[128], sNb[128];

    const int row0 = tn * 128, col0 = tm * 128;
    if (t < 128) {
        int n = row0 + t;
        sNa[t] = (n < N) ? nrm[b * N + n] : __builtin_inff();
    } else {
        int m = col0 + (t - 128);
        sNb[t - 128] = (m < N) ? nrm[B * N + b * N + m] : __builtin_inff();
    }

    // staging: wave wv issues 4 A + 4 B 16B-chunk instrs per K-step.
    // LDS linear; source col-group XOR-pre-swizzled (rule 21 both-sides).
    size_t aofs[4], bofs[4];
    int ldso[4];
#pragma unroll
    for (int s = 0; s < 4; ++s) {
        int c = (wv * 4 + s) * 64 + lane;
        int rl = c >> 3;
        int grp = (c & 7) ^ (rl & 7);
        int ga = row0 + rl; if (ga > N - 1) ga = N - 1;
        int gb = col0 + rl; if (gb > N - 1) gb = N - 1;
        aofs[s] = ((size_t)b * N + ga) * C + grp * 8;
        bofs[s] = ((size_t)b * N + gb) * C + grp * 8;
        ldso[s] = (wv * 4 + s) * 512;
    }

    f32x4 acc[4][4];
#pragma unroll
    for (int i = 0; i < 4; ++i)
#pragma unroll
        for (int j = 0; j < 4; ++j) acc[i][j] = (f32x4){0.f, 0.f, 0.f, 0.f};

    for (int kt = 0; kt < 8; ++kt) {
        int ke = kt * 64;
#pragma unroll
        for (int s = 0; s < 4; ++s) {
            gload_lds16(abf + aofs[s] + ke, &Als[ldso[s]]);
            gload_lds16(bbf + bofs[s] + ke, &Bls[ldso[s]]);
        }
        __syncthreads();   // vmcnt(0) drain; other 3 blocks on this CU compute
#pragma unroll
        for (int ks = 0; ks < 2; ++ks) {
            short8 afr[4], bfr[4];
            int cb = ks * 4 + (lane >> 4);
#pragma unroll
            for (int f = 0; f < 4; ++f) {
                int ra = wr * 64 + f * 16 + (lane & 15);
                afr[f] = *(const short8*)&Als[ra * 64 + ((cb ^ (ra & 7)) << 3)];
                int rb = wc * 64 + f * 16 + (lane & 15);
                bfr[f] = *(const short8*)&Bls[rb * 64 + ((cb ^ (rb & 7)) << 3)];
            }
#pragma unroll
            for (int fi = 0; fi < 4; ++fi)
#pragma unroll
                for (int fj = 0; fj < 4; ++fj)
                    acc[fi][fj] = __builtin_amdgcn_mfma_f32_16x16x32_bf16(
                        afr[fi], bfr[fj], acc[fi][fj], 0, 0, 0);
        }
        __syncthreads();   // all LDS reads done before next stage overwrites
    }

    // ---- merged epilogue (C/D layout: col=lane&15, row=(lane>>4)*4+reg) ----
    const int g4 = (lane >> 4) << 2;
    float na4[4][4], nb4[4];
#pragma unroll
    for (int fi = 0; fi < 4; ++fi) {
        float4 v = *(const float4*)&sNa[wr * 64 + fi * 16 + g4];
        na4[fi][0] = v.x; na4[fi][1] = v.y; na4[fi][2] = v.z; na4[fi][3] = v.w;
    }
#pragma unroll
    for (int fj = 0; fj < 4; ++fj) nb4[fj] = sNb[wc * 64 + fj * 16 + (lane & 15)];

    u64(*red)[33] = (u64(*)[33])RAW;   // aliases staging (reads drained above)
    u64 ck[4] = {~0ull, ~0ull, ~0ull, ~0ull};
#pragma unroll
    for (int fi = 0; fi < 4; ++fi) {
        int rl = wr * 64 + fi * 16 + g4;
        u64 rk[4] = {~0ull, ~0ull, ~0ull, ~0ull};
#pragma unroll
        for (int fj = 0; fj < 4; ++fj) {
            unsigned colidx = (unsigned)(col0 + wc * 64 + fj * 16 + (lane & 15));
#pragma unroll
            for (int reg = 0; reg < 4; ++reg) {
                float d2 = fmaxf(na4[fi][reg] + nb4[fj] - 2.f * acc[fi][fj][reg], 0.f);
                u64 hv = ((u64)__float_as_uint(d2) << 32);
                rk[reg] = umin64(rk[reg], hv | colidx);
                ck[fj] = umin64(ck[fj], hv | (unsigned)(row0 + rl + reg));
            }
        }
#pragma unroll
        for (int reg = 0; reg < 4; ++reg)
            red[rl + reg][(wc << 4) | (lane & 15)] = rk[reg];
    }
    // dir1: reduce over row-groups within wave, then across waves via atomic
#pragma unroll
    for (int fj = 0; fj < 4; ++fj) {
        u64 best = ck[fj];
        best = umin64(best, __shfl_xor(best, 16, 64));
        best = umin64(best, __shfl_xor(best, 32, 64));
        if (lane < 16) {
            int m = col0 + wc * 64 + fj * 16 + lane;
            if (m < N) atomicMin(&rowkey[(size_t)B * N + (size_t)b * N + m], best);
        }
    }
    __syncthreads();
    // dir0: one thread per row scans 32 candidates
    if (t < 128) {
        u64 best = red[t][0];
#pragma unroll
        for (int x = 1; x < 32; ++x) best = umin64(best, red[t][x]);
        int n = row0 + t;
        if (n < N) atomicMin(&rowkey[(size_t)b * N + n], best);
    }
}

// ---------------------------------------------------------------------------
// Location-space distances (C=2): dirs 2 and 3. Plain stores (no init
// needed). Candidate table in LDS as float4 {x, y, |p|^2, 0}.
// ---------------------------------------------------------------------------
__global__ __launch_bounds__(256) void loc_dist_kernel(
    const float* __restrict__ l1, const float* __restrict__ l2,
    u64* __restrict__ rowkey) {
    const int dir = blockIdx.z;
    const int b = blockIdx.y;
    const int t = threadIdx.x;
    const int n = blockIdx.x * 256 + t;
    __shared__ __align__(16) float4 s4[N];
    const float* Ap = dir ? l2 : l1;
    const float* Bp = dir ? l1 : l2;
    for (int i = t; i < N; i += 256) {
        float2 qv = ((const float2*)Bp)[b * N + i];
        s4[i] = make_float4(qv.x, qv.y, qv.x * qv.x + qv.y * qv.y, 0.f);
    }
    __syncthreads();
    if (n >= N) return;
    float2 a = ((const float2*)Ap)[b * N + n];
    float a2 = a.x * a.x + a.y * a.y;
    float nax = -2.f * a.x, nay = -2.f * a.y;
    u64 best = ~0ull;
#pragma unroll 4
    for (int mm = 0; mm < N; ++mm) {
        float4 v = s4[mm];
        float d2 = fmaxf(fmaf(nax, v.x, fmaf(nay, v.y, a2 + v.z)), 0.f);
        u64 kv = ((u64)__float_as_uint(d2) << 32) | (unsigned)mm;
        best = kv < best ? kv : best;
    }
    rowkey[(size_t)(2 + dir) * B * N + (size_t)b * N + n] = best;
}

// ---------------------------------------------------------------------------
// Per (dir, b): 256 rows with smallest NN-dist, stable, original order.
// Block (0,0) also zero-inits the loss accumulators (runs before vicreg).
// ---------------------------------------------------------------------------
__global__ __launch_bounds__(256) void select_kernel(
    const u64* __restrict__ rowkey, int* __restrict__ sel_idx,
    int* __restrict__ nn_idx, float* __restrict__ acc) {
    const int b = blockIdx.x;
    const int dir = blockIdx.y;
    const int t = threadIdx.x;
    if (b == 0 && dir == 0 && t < 8) acc[t] = 0.f;
    __shared__ u64 sk[1024];
    const u64* rk = rowkey + (size_t)dir * B * N + (size_t)b * N;
    for (int i = t; i < 1024; i += 256)
        sk[i] = (i < N) ? ((rk[i] & 0xFFFFFFFF00000000ull) | (unsigned)i) : ~0ull;
    __syncthreads();
    for (unsigned k = 2; k <= 1024; k <<= 1) {
        for (unsigned j = k >> 1; j > 0; j >>= 1) {
            for (unsigned i = t; i < 1024; i += 256) {
                unsigned ixj = i ^ j;
                if (ixj > i) {
                    u64 x = sk[i], y = sk[ixj];
                    bool up = ((i & k) == 0);
                    if ((x > y) == up) { sk[i] = y; sk[ixj] = x; }
                }
            }
            __syncthreads();
        }
    }
    unsigned myidx = (unsigned)(sk[t] & 0xFFFFFFFFull);
    __syncthreads();
    unsigned* si = (unsigned*)sk;
    si[t] = myidx;
    __syncthreads();
    for (unsigned k = 2; k <= 256; k <<= 1) {
        for (unsigned j = k >> 1; j > 0; j >>= 1) {
            unsigned i = t, ixj = i ^ j;
            if (ixj > i) {
                unsigned x = si[i], y = si[ixj];
                bool up = ((i & k) == 0);
                if ((x > y) == up) { si[i] = y; si[ixj] = x; }
            }
            __syncthreads();
        }
    }
    int sel = (int)si[t];
    sel_idx[((size_t)dir * B + b) * M + t] = sel;
    nn_idx[((size_t)dir * B + b) * M + t] = (int)(unsigned)(rk[sel] & 0xFFFFFFFFull);
}

// ---------------------------------------------------------------------------
// MFMA VICReg per (pair p, location mloc), 4-chunk-resident (R6, passing).
// ---------------------------------------------------------------------------
__global__ __launch_bounds__(256, 1) void vicreg_mfma_kernel(
    const u16* __restrict__ abf, const u16* __restrict__ bbf,
    const int* __restrict__ sel_idx, const int* __restrict__ nn_idx,
    float* __restrict__ acc) {
    const int mloc = blockIdx.x;
    const int p = blockIdx.y;
    const int t = threadIdx.x;
    const int l = t & 63, w = t >> 6;

    __shared__ __align__(16) u16 Xs[4][64 * 128];   // 64 KB
    __shared__ __align__(16) u16 Ys[4][64 * 128];   // 64 KB
    __shared__ float colpart[2][4][4][128];         // [parity][wave][stat][col] 16 KB
    __shared__ float Rsx[64], Rsy[64];
    __shared__ int xi[64], yi[64];
    __shared__ float redsc[4][4];

    if (t < 64) xi[t] = sel_idx[((size_t)p * B + t) * M + mloc];
    else if (t < 128) yi[t - 64] = nn_idx[((size_t)p * B + (t - 64)) * M + mloc];
    __syncthreads();

    const u16* Xg = (p & 1) ? bbf : abf;
    const u16* Yg = (p & 1) ? abf : bbf;
    unsigned xofs[4], yofs[4];
    int ldst[4];
#pragma unroll
    for (int s = 0; s < 4; ++s) {
        int r = w * 16 + s * 4 + (l >> 4);
        int cs = (l & 15) ^ (r & 15);
        xofs[s] = (unsigned)((r * N + xi[r]) * C + cs * 8);
        yofs[s] = (unsigned)((r * N + yi[r]) * C + cs * 8);
        ldst[s] = (w * 16 + s * 4) * 128;
    }

    // ---- stage ALL 4 chunks, then drain once ----
#pragma unroll
    for (int kc = 0; kc < 4; ++kc)
#pragma unroll
        for (int s = 0; s < 4; ++s) {
            gload_lds16(Xg + xofs[s] + kc * 128, &Xs[kc][ldst[s]]);
            gload_lds16(Yg + yofs[s] + kc * 128, &Ys[kc][ldst[s]]);
        }
    __syncthreads();   // single vmcnt(0) drain: all tiles resident

    f32x4 Gx[4], Gy[4], Z;
#pragma unroll
    for (int j = 0; j < 4; ++j) { Gx[j] = (f32x4){0,0,0,0}; Gy[j] = (f32x4){0,0,0,0}; }
    Z = (f32x4){0, 0, 0, 0};
    float stdacc = 0.f, covdacc = 0.f, reprp = 0.f;

#pragma unroll
    for (int kc = 0; kc < 4; ++kc) {
        const u16* Xc = Xs[kc];
        const u16* Yc = Ys[kc];

        // ---- MFMA Grams ----
#pragma unroll
        for (int ks = 0; ks < 4; ++ks) {
            int cb = ks * 4 + (l >> 4);
            int pe = (cb ^ (l & 15)) << 3;
            short8 ax = *(const short8*)&Xc[((w << 4) + (l & 15)) * 128 + pe];
            short8 ay = *(const short8*)&Yc[((w << 4) + (l & 15)) * 128 + pe];
            short8 bx[4], by[4];
#pragma unroll
            for (int j = 0; j < 4; ++j) {
                bx[j] = *(const short8*)&Xc[(j * 16 + (l & 15)) * 128 + pe];
                by[j] = *(const short8*)&Yc[(j * 16 + (l & 15)) * 128 + pe];
            }
#pragma unroll
            for (int j = 0; j < 4; ++j) {
                Gx[j] = __builtin_amdgcn_mfma_f32_16x16x32_bf16(ax, bx[j], Gx[j], 0, 0, 0);
                Gy[j] = __builtin_amdgcn_mfma_f32_16x16x32_bf16(ay, by[j], Gy[j], 0, 0, 0);
            }
            Z = __builtin_amdgcn_mfma_f32_16x16x32_bf16(ax, ay, Z, 0, 0, 0);
        }

        // ---- column stats: per-wave partials, rows 16w..16w+15 ----
        {
            int c4 = (l & 31) << 2;
            int cc = c4 >> 3, h = (c4 >> 2) & 1;
            int g2 = (w << 1) + (l >> 5);
            float s1x0 = 0, s1x1 = 0, s1x2 = 0, s1x3 = 0;
            float s2x0 = 0, s2x1 = 0, s2x2 = 0, s2x3 = 0;
            float s1y0 = 0, s1y1 = 0, s1y2 = 0, s1y3 = 0;
            float s2y0 = 0, s2y1 = 0, s2y2 = 0, s2y3 = 0;
#pragma unroll
            for (int rr = 0; rr < 8; ++rr) {
                int r = g2 * 8 + rr;
                int off = r * 128 + ((cc ^ (r & 15)) << 3) + h * 4;
                ushort4 vx = *(const ushort4*)&Xc[off];
                ushort4 vy = *(const ushort4*)&Yc[off];
                float x0 = b2f(vx.x), x1 = b2f(vx.y), x2 = b2f(vx.z), x3 = b2f(vx.w);
                float y0 = b2f(vy.x), y1 = b2f(vy.y), y2 = b2f(vy.z), y3 = b2f(vy.w);
                s1x0 += x0; s1x1 += x1; s1x2 += x2; s1x3 += x3;
                s2x0 = fmaf(x0, x0, s2x0); s2x1 = fmaf(x1, x1, s2x1);
                s2x2 = fmaf(x2, x2, s2x2); s2x3 = fmaf(x3, x3, s2x3);
                s1y0 += y0; s1y1 += y1; s1y2 += y2; s1y3 += y3;
                s2y0 = fmaf(y0, y0, s2y0); s2y1 = fmaf(y1, y1, s2y1);
                s2y2 = fmaf(y2, y2, s2y2); s2y3 = fmaf(y3, y3, s2y3);
            }
            s1x0 += __shfl_xor(s1x0, 32, 64); s1x1 += __shfl_xor(s1x1, 32, 64);
            s1x2 += __shfl_xor(s1x2, 32, 64); s1x3 += __shfl_xor(s1x3, 32, 64);
            s2x0 += __shfl_xor(s2x0, 32, 64); s2x1 += __shfl_xor(s2x1, 32, 64);
            s2x2 += __shfl_xor(s2x2, 32, 64); s2x3 += __shfl_xor(s2x3, 32, 64);
            s1y0 += __shfl_xor(s1y0, 32, 64); s1y1 += __shfl_xor(s1y1, 32, 64);
            s1y2 += __shfl_xor(s1y2, 32, 64); s1y3 += __shfl_xor(s1y3, 32, 64);
            s2y0 += __shfl_xor(s2y0, 32, 64); s2y1 += __shfl_xor(s2y1, 32, 64);
            s2y2 += __shfl_xor(s2y2, 32, 64); s2y3 += __shfl_xor(s2y3, 32, 64);
            if (l < 32) {
                *(float4*)&colpart[kc & 1][w][0][c4] = make_float4(s1x0, s1x1, s1x2, s1x3);
                *(float4*)&colpart[kc & 1][w][1][c4] = make_float4(s2x0, s2x1, s2x2, s2x3);
                *(float4*)&colpart[kc & 1][w][2][c4] = make_float4(s1y0, s1y1, s1y2, s1y3);
                *(float4*)&colpart[kc & 1][w][3][c4] = make_float4(s2y0, s2y1, s2y2, s2y3);
            }
        }
        __syncthreads();   // stats of chunk kc visible; parity buffer isolates
                           // these reads from chunk kc+1's writes

        if (t < 128) {
            float s1x = 0, s2x = 0, s1y = 0, s2y = 0;
#pragma unroll
            for (int ww = 0; ww < 4; ++ww) {
                s1x += colpart[kc & 1][ww][0][t]; s2x += colpart[kc & 1][ww][1][t];
                s1y += colpart[kc & 1][ww][2][t]; s2y += colpart[kc & 1][ww][3][t];
            }
            float sx = s2x - s1x * s1x * (1.f / 64.f);
            float sy = s2y - s1y * s1y * (1.f / 64.f);
            stdacc += fmaxf(0.f, 1.f - sqrtf(sx * (1.f / 63.f) + 1e-4f)) +
                      fmaxf(0.f, 1.f - sqrtf(sy * (1.f / 63.f) + 1e-4f));
            covdacc += sx * sx + sy * sy;
            reprp += s2x + s2y;
        }
    }

    // ---- epilogue ----
    float zd = 0.f;
    {
        int rbase = (l >> 4) << 2, col = l & 15;
#pragma unroll
        for (int reg = 0; reg < 4; ++reg)
            zd += (col == rbase + reg) ? Z[reg] : 0.f;
    }
    float rsx[4], rsy[4];
#pragma unroll
    for (int reg = 0; reg < 4; ++reg) {
        rsx[reg] = Gx[0][reg] + Gx[1][reg] + Gx[2][reg] + Gx[3][reg];
        rsy[reg] = Gy[0][reg] + Gy[1][reg] + Gy[2][reg] + Gy[3][reg];
    }
#pragma unroll
    for (int off = 1; off < 16; off <<= 1)
#pragma unroll
        for (int reg = 0; reg < 4; ++reg) {
            rsx[reg] += __shfl_xor(rsx[reg], off, 64);
            rsy[reg] += __shfl_xor(rsy[reg], off, 64);
        }
    if ((l & 15) == 0) {
#pragma unroll
        for (int reg = 0; reg < 4; ++reg) {
            Rsx[(w << 4) + ((l >> 4) << 2) + reg] = rsx[reg];
            Rsy[(w << 4) + ((l >> 4) << 2) + reg] = rsy[reg];
        }
    }
    __syncthreads();
    float myx = Rsx[l], myy = Rsy[l];
#pragma unroll
    for (int off = 1; off < 64; off <<= 1) {
        myx += __shfl_xor(myx, off, 64);
        myy += __shfl_xor(myy, off, 64);
    }
    float tX = myx * (1.f / 4096.f), tY = myy * (1.f / 4096.f);
    float kn = 0.f;
#pragma unroll
    for (int j = 0; j < 4; ++j) {
        float cX = Rsx[(j << 4) + (l & 15)] * (1.f / 64.f);
        float cY = Rsy[(j << 4) + (l & 15)] * (1.f / 64.f);
#pragma unroll
        for (int reg = 0; reg < 4; ++reg) {
            float K1 = Gx[j][reg] - rsx[reg] * (1.f / 64.f) - cX + tX;
            kn = fmaf(K1, K1, kn);
            float K2 = Gy[j][reg] - rsy[reg] * (1.f / 64.f) - cY + tY;
            kn = fmaf(K2, K2, kn);
        }
    }

    float v0 = reprp - 2.f * zd, v1 = stdacc, v2 = covdacc, v3 = kn;
#pragma unroll
    for (int off = 1; off < 64; off <<= 1) {
        v0 += __shfl_xor(v0, off, 64);
        v1 += __shfl_xor(v1, off, 64);
        v2 += __shfl_xor(v2, off, 64);
        v3 += __shfl_xor(v3, off, 64);
    }
    if (l == 0) { redsc[w][0] = v0; redsc[w][1] = v1; redsc[w][2] = v2; redsc[w][3] = v3; }
    __syncthreads();
    if (t == 0) {
        float r0 = 0, r1 = 0, r2 = 0, r3 = 0;
#pragma unroll
        for (int ww = 0; ww < 4; ++ww) {
            r0 += redsc[ww][0]; r1 += redsc[ww][1];
            r2 += redsc[ww][2]; r3 += redsc[ww][3];
        }
        atomicAdd(&acc[0], r0);
        atomicAdd(&acc[1], r1);
        atomicAdd(&acc[2], r3 - r2);
    }
}

// ---------------------------------------------------------------------------
// FALLBACK fp32 path kernels (only if ws can't hold bf16 copies)
// ---------------------------------------------------------------------------
__global__ __launch_bounds__(256) void norms_kernel(const float* __restrict__ m1,
                                                    const float* __restrict__ m2,
                                                    float* __restrict__ nrm) {
    int w = blockIdx.x * 4 + (threadIdx.x >> 6);
    int lane = threadIdx.x & 63;
    if (w >= 2 * B * N) return;
    const float* src = (w < B * N) ? m1 : m2;
    int row = (w < B * N) ? w : w - B * N;
    const float4* p = (const float4*)(src + (size_t)row * C);
    float s = 0.f;
#pragma unroll
    for (int i = 0; i < 2; ++i) {
        float4 v = p[lane + i * 64];
        s += v.x * v.x + v.y * v.y + v.z * v.z + v.w * v.w;
    }
#pragma unroll
    for (int off = 32; off > 0; off >>= 1) s += __shfl_down(s, off, 64);
    if (lane == 0) nrm[w] = s;
}

__global__ __launch_bounds__(256) void feat_dist_kernel(
    const float* __restrict__ m1, const float* __restrict__ m2,
    const float* __restrict__ nrm, u64* __restrict__ rowkey) {
    const int b = blockIdx.z;
    const int tn = blockIdx.x, tm = blockIdx.y;
    __shared__ float As[64][68];
    __shared__ float Bt[64][68];
    __shared__ u64 red[64][16];
    const int t = threadIdx.x;
    const int ty = t >> 4, tx = t & 15;
    float acc[4][4] = {};
    const float* A = m1 + (size_t)b * N * C;
    const float* Bm = m2 + (size_t)b * N * C;

    for (int k0 = 0; k0 < C; k0 += 64) {
#pragma unroll
        for (int it = 0; it < 4; ++it) {
            int idx = t + it * 256;
            int r = idx >> 4, cc = (idx & 15) << 2;
            int n = tn * 64 + r;
            float4 v = make_float4(0.f, 0.f, 0.f, 0.f);
            if (n < N) v = *(const float4*)(A + (size_t)n * C + k0 + cc);
            *(float4*)&As[r][cc] = v;
            int mm = tm * 64 + r;
            float4 w = make_float4(0.f, 0.f, 0.f, 0.f);
            if (mm < N) w = *(const float4*)(Bm + (size_t)mm * C + k0 + cc);
            Bt[cc + 0][r] = w.x; Bt[cc + 1][r] = w.y;
            Bt[cc + 2][r] = w.z; Bt[cc + 3][r] = w.w;
        }
        __syncthreads();
#pragma unroll 4
        for (int kq = 0; kq < 64; kq += 4) {
            float aa[4][4], bb[4][4];
#pragma unroll
            for (int i = 0; i < 4; ++i) {
                float4 v = *(const float4*)&As[ty * 4 + i][kq];
                aa[i][0] = v.x; aa[i][1] = v.y; aa[i][2] = v.z; aa[i][3] = v.w;
            }
#pragma unroll
            for (int qq = 0; qq < 4; ++qq) {
                float4 v = *(const float4*)&Bt[kq + qq][tx * 4];
                bb[qq][0] = v.x; bb[qq][1] = v.y; bb[qq][2] = v.z; bb[qq][3] = v.w;
            }
#pragma unroll
            for (int qq = 0; qq < 4; ++qq)
#pragma unroll
                for (int i = 0; i < 4; ++i)
#pragma unroll
                    for (int j = 0; j < 4; ++j)
                        acc[i][j] = fmaf(aa[i][qq], bb[qq][j], acc[i][j]);
        }
        __syncthreads();
    }

    u64 rk[4] = {~0ull, ~0ull, ~0ull, ~0ull};
    u64 ck[4] = {~0ull, ~0ull, ~0ull, ~0ull};
    const float* nr1 = nrm;
    const float* nr2 = nrm + B * N;
#pragma unroll
    for (int i = 0; i < 4; ++i) {
        int n = tn * 64 + ty * 4 + i;
        if (n >= N) continue;
        float a2 = nr1[b * N + n];
#pragma unroll
        for (int j = 0; j < 4; ++j) {
            int mm = tm * 64 + tx * 4 + j;
            if (mm >= N) continue;
            float b2 = nr2[b * N + mm];
            float d2 = a2 + b2 - 2.f * acc[i][j];
            unsigned vb = __float_as_uint(fmaxf(d2, 0.f));
            u64 kv = ((u64)vb << 32);
            rk[i] = umin64(rk[i], kv | (unsigned)mm);
            ck[j] = umin64(ck[j], kv | (unsigned)n);
        }
    }
#pragma unroll
    for (int i = 0; i < 4; ++i) red[ty * 4 + i][tx] = rk[i];
    __syncthreads();
    if (t < 64) {
        u64 best = red[t][0];
#pragma unroll
        for (int x = 1; x < 16; ++x) best = umin64(best, red[t][x]);
        int n = tn * 64 + t;
        if (n < N && best != ~0ull)
            atomicMin(&rowkey[(size_t)b * N + n], best);
    }
    __syncthreads();
#pragma unroll
    for (int j = 0; j < 4; ++j) red[tx * 4 + j][ty] = ck[j];
    __syncthreads();
    if (t < 64) {
        u64 best = red[t][0];
#pragma unroll
        for (int x = 1; x < 16; ++x) best = umin64(best, red[t][x]);
        int mm = tm * 64 + t;
        if (mm < N && best != ~0ull)
            atomicMin(&rowkey[(size_t)B * N + (size_t)b * N + mm], best);
    }
}

__device__ __forceinline__ float blockReduce(float v, float* redb, int t) {
    __syncthreads();
    redb[t] = v;
    __syncthreads();
    for (int s = 128; s > 0; s >>= 1) {
        if (t < s) redb[t] += redb[t + s];
        __syncthreads();
    }
    return redb[0];
}

__global__ __launch_bounds__(256) void vicreg_kernel(
    const float* __restrict__ m1, const float* __restrict__ m2,
    const int* __restrict__ sel_idx, const int* __restrict__ nn_idx,
    float* __restrict__ acc) {
    const int mloc = blockIdx.x;
    const int p = blockIdx.y;
    const int t = threadIdx.x;
    const float* X = (p & 1) ? m2 : m1;
    const float* Y = (p & 1) ? m1 : m2;
    __shared__ float Xs[64][65];
    __shared__ float Ys[64][65];
    __shared__ int xi[64], yi[64];
    __shared__ float pst[192][5];
    __shared__ float Rs[64];
    __shared__ float Tsh;
    __shared__ float redb[256];

    if (t < 64) {
        xi[t] = sel_idx[((size_t)p * B + t) * M + mloc];
        yi[t] = nn_idx[((size_t)p * B + t) * M + mloc];
    }
    __syncthreads();

    float Gx[4][4] = {}, Gy[4][4] = {};
    float stdx = 0, stdy = 0, covdx = 0, covdy = 0, repr = 0;
    const int i0 = (t >> 4) << 2, j0 = (t & 15) << 2;

    for (int c0 = 0; c0 < C; c0 += 64) {
#pragma unroll
        for (int it = 0; it < 4; ++it) {
            int fidx = t + it * 256;
            int r = fidx >> 4, cc = (fidx & 15) << 2;
            float4 v = *(const float4*)(X + ((size_t)r * N + xi[r]) * C + c0 + cc);
            Xs[r][cc] = v.x; Xs[r][cc + 1] = v.y; Xs[r][cc + 2] = v.z; Xs[r][cc + 3] = v.w;
            float4 w = *(const float4*)(Y + ((size_t)r * N + yi[r]) * C + c0 + cc);
            Ys[r][cc] = w.x; Ys[r][cc + 1] = w.y; Ys[r][cc + 2] = w.z; Ys[r][cc + 3] = w.w;
        }
        __syncthreads();
#pragma unroll 4
        for (int k = 0; k < 64; ++k) {
            float ax[4], bx[4], ay[4], by[4];
#pragma unroll
            for (int i = 0; i < 4; ++i) { ax[i] = Xs[i0 + i][k]; ay[i] = Ys[i0 + i][k]; }
#pragma unroll
            for (int j = 0; j < 4; ++j) { bx[j] = Xs[j0 + j][k]; by[j] = Ys[j0 + j][k]; }
#pragma unroll
            for (int i = 0; i < 4; ++i)
#pragma unroll
                for (int j = 0; j < 4; ++j) {
                    Gx[i][j] = fmaf(ax[i], bx[j], Gx[i][j]);
                    Gy[i][j] = fmaf(ay[i], by[j], Gy[i][j]);
                }
        }
        {
            float s1x = 0, s2x = 0, s1y = 0, s2y = 0, sxy = 0;
            int col = t & 63, g = t >> 6;
            for (int r = g * 16; r < g * 16 + 16; ++r) {
                float xv = Xs[r][col], yv = Ys[r][col];
                s1x += xv; s2x += xv * xv;
                s1y += yv; s2y += yv * yv;
                sxy += xv * yv;
            }
            if (g) {
                float* qq = pst[(g - 1) * 64 + col];
                qq[0] = s1x; qq[1] = s2x; qq[2] = s1y; qq[3] = s2y; qq[4] = sxy;
            }
            __syncthreads();
            if (g == 0) {
#pragma unroll
                for (int gg = 0; gg < 3; ++gg) {
                    float* qq = pst[gg * 64 + col];
                    s1x += qq[0]; s2x += qq[1]; s1y += qq[2]; s2y += qq[3]; sxy += qq[4];
                }
                float xb = s1x * (1.f / 64.f);
                float sx = s2x - 64.f * xb * xb;
                float yb = s1y * (1.f / 64.f);
                float sy = s2y - 64.f * yb * yb;
                stdx += fmaxf(0.f, 1.f - sqrtf(sx * (1.f / 63.f) + 1e-4f));
                stdy += fmaxf(0.f, 1.f - sqrtf(sy * (1.f / 63.f) + 1e-4f));
                covdx += sx * sx;
                covdy += sy * sy;
                repr += s2x + s2y - 2.f * sxy;
            }
            __syncthreads();
        }
    }

    float knx = 0.f, kny = 0.f;
    float (*Gs)[65] = (float(*)[65]) & Xs[0][0];
    __syncthreads();
#pragma unroll
    for (int i = 0; i < 4; ++i)
#pragma unroll
        for (int j = 0; j < 4; ++j) Gs[i0 + i][j0 + j] = Gx[i][j];
    __syncthreads();
    if (t < 64) {
        float r = 0;
        for (int j = 0; j < 64; ++j) r += Gs[t][j];
        Rs[t] = r;
    }
    __syncthreads();
    if (t < 64) {
        float r = Rs[t];
#pragma unroll
        for (int off = 32; off > 0; off >>= 1) r += __shfl_down(r, off, 64);
        if (t == 0) Tsh = r;
    }
    __syncthreads();
    {
        float T = Tsh * (1.f / 4096.f);
#pragma unroll
        for (int i = 0; i < 4; ++i)
#pragma unroll
            for (int j = 0; j < 4; ++j) {
                float Kij = Gx[i][j] - (Rs[i0 + i] + Rs[j0 + j]) * (1.f / 64.f) + T;
                knx = fmaf(Kij, Kij, knx);
            }
    }
    __syncthreads();
#pragma unroll
    for (int i = 0; i < 4; ++i)
#pragma unroll
        for (int j = 0; j < 4; ++j) Gs[i0 + i][j0 + j] = Gy[i][j];
    __syncthreads();
    if (t < 64) {
        float r = 0;
        for (int j = 0; j < 64; ++j) r += Gs[t][j];
        Rs[t] = r;
    }
    __syncthreads();
    if (t < 64) {
        float r = Rs[t];
#pragma unroll
        for (int off = 32; off > 0; off >>= 1) r += __shfl_down(r, off, 64);
        if (t == 0) Tsh = r;
    }
    __syncthreads();
    {
        float T = Tsh * (1.f / 4096.f);
#pragma unroll
        for (int i = 0; i < 4; ++i)
#pragma unroll
            for (int j = 0; j < 4; ++j) {
                float Kij = Gy[i][j] - (Rs[i0 + i] + Rs[j0 + j]) * (1.f / 64.f) + T;
                kny = fmaf(Kij, Kij, kny);
            }
    }

    float v_repr = blockReduce(repr, redb, t);
    float v_std = blockReduce(stdx + stdy, redb, t);
    float v_covd = blockReduce(covdx + covdy, redb, t);
    float v_kn = blockReduce(knx + kny, redb, t);
    if (t == 0) {
        atomicAdd(&acc[0], v_repr);
        atomicAdd(&acc[1], v_std);
        atomicAdd(&acc[2], v_kn - v_covd);
    }
}

// ---------------------------------------------------------------------------
__global__ void finalize_kernel(const float* __restrict__ acc, float* __restrict__ out) {
    if (threadIdx.x == 0 && blockIdx.x == 0) {
        float repr = 25.f * acc[0] / ((float)B * (float)M * (float)C);
        float stdl = 12.5f * acc[1] / ((float)M * (float)C);
        float cov = acc[2] / (63.f * 63.f * (float)C * 2.f) / (float)M;
        out[0] = repr + stdl + cov;
    }
}

// ---------------------------------------------------------------------------
extern "C" void kernel_launch(void* const* d_in, const int* in_sizes, int n_in,
                              void* d_out, int out_size, void* d_ws, size_t ws_size,
                              hipStream_t stream) {
    const float* m1 = (const float*)d_in[0];
    const float* m2 = (const float*)d_in[1];
    const float* l1 = (const float*)d_in[2];
    const float* l2 = (const float*)d_in[3];
    float* out = (float*)d_out;
    char* ws = (char*)d_ws;

    u64* rowkey = (u64*)ws;                                   // [4][B][N]
    size_t off = (size_t)4 * B * N * sizeof(u64);
    float* nrm = (float*)(ws + off); off += (size_t)2 * B * N * sizeof(float);
    int* sel_idx = (int*)(ws + off); off += (size_t)4 * B * M * sizeof(int);
    int* nn_idx = (int*)(ws + off);  off += (size_t)4 * B * M * sizeof(int);
    float* acc = (float*)(ws + off); off += 256;
    off = (off + 255) & ~(size_t)255;
    u16* abf = (u16*)(ws + off);
    u16* bbf = abf + (size_t)B * N * C;
    size_t need = off + (size_t)2 * B * N * C * sizeof(u16);
    bool use_mfma = ws_size >= need;          // ws_size fixed -> deterministic

    // ws is NOT re-poisoned between replays: re-init everything we read.
    // Only dirs 0,1 need ~0 keys (feat uses atomicMin); loc_dist plain-stores
    // dirs 2,3; acc is zeroed by select_kernel (runs before vicreg).
    hipMemsetAsync(rowkey, 0xFF, (size_t)2 * B * N * sizeof(u64), stream);
    if (use_mfma) {
        convnorm_kernel<<<dim3(2 * B * N / 4), dim3(256), 0, stream>>>(m1, m2, abf, bbf, nrm);
        feat_mfma_kernel<<<dim3(64 * 49), dim3(256), 0, stream>>>(abf, bbf, nrm, rowkey);
    } else {
        norms_kernel<<<dim3(2 * B * N / 4), dim3(256), 0, stream>>>(m1, m2, nrm);
        feat_dist_kernel<<<dim3(13, 13, B), dim3(256), 0, stream>>>(m1, m2, nrm, rowkey);
    }
    loc_dist_kernel<<<dim3((N + 255) / 256, B, 2), dim3(256), 0, stream>>>(l1, l2, rowkey);
    select_kernel<<<dim3(B, 4), dim3(256), 0, stream>>>(rowkey, sel_idx, nn_idx, acc);
    if (use_mfma) {
        vicreg_mfma_kernel<<<dim3(M, 4), dim3(256), 0, stream>>>(abf, bbf, sel_idx, nn_idx, acc);
    } else {
        vicreg_kernel<<<dim3(M, 4), dim3(256), 0, stream>>>(m1, m2, sel_idx, nn_idx, acc);
    }
    finalize_kernel<<<dim3(1), dim3(64), 0, stream>>>(acc, out);
}

// Round 8
// 261.492 us; speedup vs baseline: 1.0442x; 1.0442x over previous
//
#include <hip/hip_runtime.h>
#include <stdint.h>

#define B 64
#define N 784
#define C 512
#define M 256

typedef unsigned long long u64;
typedef unsigned short u16;
typedef __attribute__((ext_vector_type(8))) short short8;
typedef __attribute__((ext_vector_type(4))) float f32x4;

static __device__ __forceinline__ u64 umin64(u64 a, u64 b) { return a < b ? a : b; }

static __device__ __forceinline__ u16 f2bf(float x) {   // RNE fp32 -> bf16
    unsigned u = __float_as_uint(x);
    return (u16)((u + 0x7FFFu + ((u >> 16) & 1u)) >> 16);
}
static __device__ __forceinline__ float b2f(u16 v) {
    return __uint_as_float((unsigned)v << 16);
}

static __device__ __forceinline__ void gload_lds16(const u16* g, u16* l) {
    __builtin_amdgcn_global_load_lds((const __attribute__((address_space(1))) void*)g,
                                     (__attribute__((address_space(3))) void*)l, 16, 0, 0);
}

// ---------------------------------------------------------------------------
// fused fp32->bf16 convert + row |x|^2 norms. One wave per row (512 floats).
// ---------------------------------------------------------------------------
__global__ __launch_bounds__(256) void convnorm_kernel(
    const float* __restrict__ m1, const float* __restrict__ m2,
    u16* __restrict__ abf, u16* __restrict__ bbf, float* __restrict__ nrm) {
    int w = blockIdx.x * 4 + (threadIdx.x >> 6);
    int lane = threadIdx.x & 63;
    if (w >= 2 * B * N) return;
    const float* src = (w < B * N) ? m1 : m2;
    u16* dst = (w < B * N) ? abf : bbf;
    int row = (w < B * N) ? w : w - B * N;
    const float4* p = (const float4*)(src + (size_t)row * C);
    u64* q = (u64*)(dst + (size_t)row * C);
    float s = 0.f;
#pragma unroll
    for (int i = 0; i < 2; ++i) {
        int idx = lane + i * 64;
        float4 v = p[idx];
        s += v.x * v.x + v.y * v.y + v.z * v.z + v.w * v.w;
        q[idx] = (u64)f2bf(v.x) | ((u64)f2bf(v.y) << 16) |
                 ((u64)f2bf(v.z) << 32) | ((u64)f2bf(v.w) << 48);
    }
#pragma unroll
    for (int off = 32; off > 0; off >>= 1) s += __shfl_down(s, off, 64);
    if (lane == 0) nrm[w] = s;
}

// ---------------------------------------------------------------------------
// MFMA feature-distance with T4 counted vmcnt (never 0 in the main loop):
//  dbuf LDS; per iter: issue stage(kt+1) -> vmcnt(8) (tile kt's loads are the
//  8 oldest; the 8 new stay IN FLIGHT across the barrier) -> s_barrier ->
//  compute -> lgkmcnt(0) + s_barrier (WAR before next overwrite).
//  This removes the per-K-step full vmem drain (m233's ~72% stall; m218's
//  counted-vs-drain0 = +38-73%). Epilogue u64 table aliases the LDS bufs.
// 128x128 tile, BK=64, 4 waves (2x2). Source chunk pre-XOR-swizzled (rule 21).
// ---------------------------------------------------------------------------
__global__ __launch_bounds__(256, 2) void feat_mfma_kernel(
    const u16* __restrict__ abf, const u16* __restrict__ bbf,
    const float* __restrict__ nrm, u64* __restrict__ rowkey) {
    // decode: id = ((b>>3)*49 + tile)*8 + (b&7)  (batch->XCD affinity)
    int id = blockIdx.x;
    int xcd = id & 7;
    int q = id >> 3;
    int hi = q / 49, t49 = q - hi * 49;
    int b = hi * 8 + xcd;
    int tn = t49 / 7, tm = t49 - tn * 7;

    const int t = threadIdx.x;
    const int lane = t & 63, wv = t >> 6;
    const int wr = wv >> 1, wc = wv & 1;

    // union: 2 staging bufs (A 16KB + B 16KB each) / epilogue red[128][33] u64
    __shared__ __align__(16) unsigned char RAW[65536];
    __shared__ float sNa[128], sNb[128];

    const int row0 = tn * 128, col0 = tm * 128;
    if (t < 128) {
        int n = row0 + t;
        sNa[t] = (n < N) ? nrm[b * N + n] : __builtin_inff();
    } else {
        int m = col0 + (t - 128);
        sNb[t - 128] = (m < N) ? nrm[B * N + b * N + m] : __builtin_inff();
    }

    // staging: wave wv issues 4 A + 4 B 16B-chunk instrs per K-step.
    // LDS linear; source col-group XOR-pre-swizzled (rule 21 both-sides).
    size_t aofs[4], bofs[4];
    int ldso[4];
#pragma unroll
    for (int s = 0; s < 4; ++s) {
        int c = (wv * 4 + s) * 64 + lane;
        int rl = c >> 3;
        int grp = (c & 7) ^ (rl & 7);
        int ga = row0 + rl; if (ga > N - 1) ga = N - 1;
        int gb = col0 + rl; if (gb > N - 1) gb = N - 1;
        aofs[s] = ((size_t)b * N + ga) * C + grp * 8;
        bofs[s] = ((size_t)b * N + gb) * C + grp * 8;
        ldso[s] = (wv * 4 + s) * 512;
    }

    f32x4 acc[4][4];
#pragma unroll
    for (int i = 0; i < 4; ++i)
#pragma unroll
        for (int j = 0; j < 4; ++j) acc[i][j] = (f32x4){0.f, 0.f, 0.f, 0.f};

    // prologue: stage K-step 0 into buf 0 (8 loads/wave, stay in flight)
    {
        u16* A0 = (u16*)RAW;
        u16* B0 = A0 + 8192;
#pragma unroll
        for (int s = 0; s < 4; ++s) {
            gload_lds16(abf + aofs[s], &A0[ldso[s]]);
            gload_lds16(bbf + bofs[s], &B0[ldso[s]]);
        }
    }

    for (int kt = 0; kt < 8; ++kt) {
        const int cur = kt & 1;
        if (kt < 7) {
            int ke = (kt + 1) * 64;
            u16* An = (u16*)(RAW + (cur ^ 1) * 32768);
            u16* Bn = An + 8192;
#pragma unroll
            for (int s = 0; s < 4; ++s) {
                gload_lds16(abf + aofs[s] + ke, &An[ldso[s]]);
                gload_lds16(bbf + bofs[s] + ke, &Bn[ldso[s]]);
            }
            // 16 outstanding; wait until only the 8 newest (tile kt+1) remain
            asm volatile("s_waitcnt vmcnt(8)" ::: "memory");
        } else {
            asm volatile("s_waitcnt vmcnt(0)" ::: "memory");
        }
        __builtin_amdgcn_s_barrier();   // tile kt landed for ALL waves

        const u16* Als = (const u16*)(RAW + cur * 32768);
        const u16* Bls = Als + 8192;
#pragma unroll
        for (int ks = 0; ks < 2; ++ks) {
            short8 afr[4], bfr[4];
            int cb = ks * 4 + (lane >> 4);
#pragma unroll
            for (int f = 0; f < 4; ++f) {
                int ra = wr * 64 + f * 16 + (lane & 15);
                afr[f] = *(const short8*)&Als[ra * 64 + ((cb ^ (ra & 7)) << 3)];
                int rb = wc * 64 + f * 16 + (lane & 15);
                bfr[f] = *(const short8*)&Bls[rb * 64 + ((cb ^ (rb & 7)) << 3)];
            }
#pragma unroll
            for (int fi = 0; fi < 4; ++fi)
#pragma unroll
                for (int fj = 0; fj < 4; ++fj)
                    acc[fi][fj] = __builtin_amdgcn_mfma_f32_16x16x32_bf16(
                        afr[fi], bfr[fj], acc[fi][fj], 0, 0, 0);
        }
        asm volatile("s_waitcnt lgkmcnt(0)" ::: "memory");  // my reads done
        __builtin_amdgcn_s_barrier();   // all waves' reads done before overwrite
    }

    // ---- merged epilogue (C/D layout: col=lane&15, row=(lane>>4)*4+reg) ----
    const int g4 = (lane >> 4) << 2;
    float na4[4][4], nb4[4];
#pragma unroll
    for (int fi = 0; fi < 4; ++fi) {
        float4 v = *(const float4*)&sNa[wr * 64 + fi * 16 + g4];
        na4[fi][0] = v.x; na4[fi][1] = v.y; na4[fi][2] = v.z; na4[fi][3] = v.w;
    }
#pragma unroll
    for (int fj = 0; fj < 4; ++fj) nb4[fj] = sNb[wc * 64 + fj * 16 + (lane & 15)];

    u64(*red)[33] = (u64(*)[33])RAW;   // aliases staging (reads drained above)
    u64 ck[4] = {~0ull, ~0ull, ~0ull, ~0ull};
#pragma unroll
    for (int fi = 0; fi < 4; ++fi) {
        int rl = wr * 64 + fi * 16 + g4;
        u64 rk[4] = {~0ull, ~0ull, ~0ull, ~0ull};
#pragma unroll
        for (int fj = 0; fj < 4; ++fj) {
            unsigned colidx = (unsigned)(col0 + wc * 64 + fj * 16 + (lane & 15));
#pragma unroll
            for (int reg = 0; reg < 4; ++reg) {
                float d2 = fmaxf(na4[fi][reg] + nb4[fj] - 2.f * acc[fi][fj][reg], 0.f);
                u64 hv = ((u64)__float_as_uint(d2) << 32);
                rk[reg] = umin64(rk[reg], hv | colidx);
                ck[fj] = umin64(ck[fj], hv | (unsigned)(row0 + rl + reg));
            }
        }
#pragma unroll
        for (int reg = 0; reg < 4; ++reg)
            red[rl + reg][(wc << 4) | (lane & 15)] = rk[reg];
    }
    // dir1: reduce over row-groups within wave, then across waves via atomic
#pragma unroll
    for (int fj = 0; fj < 4; ++fj) {
        u64 best = ck[fj];
        best = umin64(best, __shfl_xor(best, 16, 64));
        best = umin64(best, __shfl_xor(best, 32, 64));
        if (lane < 16) {
            int m = col0 + wc * 64 + fj * 16 + lane;
            if (m < N) atomicMin(&rowkey[(size_t)B * N + (size_t)b * N + m], best);
        }
    }
    __syncthreads();
    // dir0: one thread per row scans 32 candidates
    if (t < 128) {
        u64 best = red[t][0];
#pragma unroll
        for (int x = 1; x < 32; ++x) best = umin64(best, red[t][x]);
        int n = row0 + t;
        if (n < N) atomicMin(&rowkey[(size_t)b * N + n], best);
    }
}

// ---------------------------------------------------------------------------
// Location-space distances (C=2): dirs 2 and 3. Plain stores (no init
// needed). Candidate table in LDS as float4 {x, y, |p|^2, 0}.
// ---------------------------------------------------------------------------
__global__ __launch_bounds__(256) void loc_dist_kernel(
    const float* __restrict__ l1, const float* __restrict__ l2,
    u64* __restrict__ rowkey) {
    const int dir = blockIdx.z;
    const int b = blockIdx.y;
    const int t = threadIdx.x;
    const int n = blockIdx.x * 256 + t;
    __shared__ __align__(16) float4 s4[N];
    const float* Ap = dir ? l2 : l1;
    const float* Bp = dir ? l1 : l2;
    for (int i = t; i < N; i += 256) {
        float2 qv = ((const float2*)Bp)[b * N + i];
        s4[i] = make_float4(qv.x, qv.y, qv.x * qv.x + qv.y * qv.y, 0.f);
    }
    __syncthreads();
    if (n >= N) return;
    float2 a = ((const float2*)Ap)[b * N + n];
    float a2 = a.x * a.x + a.y * a.y;
    float nax = -2.f * a.x, nay = -2.f * a.y;
    u64 best = ~0ull;
#pragma unroll 4
    for (int mm = 0; mm < N; ++mm) {
        float4 v = s4[mm];
        float d2 = fmaxf(fmaf(nax, v.x, fmaf(nay, v.y, a2 + v.z)), 0.f);
        u64 kv = ((u64)__float_as_uint(d2) << 32) | (unsigned)mm;
        best = kv < best ? kv : best;
    }
    rowkey[(size_t)(2 + dir) * B * N + (size_t)b * N + n] = best;
}

// ---------------------------------------------------------------------------
// Per (dir, b): 256 rows with smallest NN-dist, stable, original order.
// Block (0,0) also zero-inits the loss accumulators (runs before vicreg).
// ---------------------------------------------------------------------------
__global__ __launch_bounds__(256) void select_kernel(
    const u64* __restrict__ rowkey, int* __restrict__ sel_idx,
    int* __restrict__ nn_idx, float* __restrict__ acc) {
    const int b = blockIdx.x;
    const int dir = blockIdx.y;
    const int t = threadIdx.x;
    if (b == 0 && dir == 0 && t < 8) acc[t] = 0.f;
    __shared__ u64 sk[1024];
    const u64* rk = rowkey + (size_t)dir * B * N + (size_t)b * N;
    for (int i = t; i < 1024; i += 256)
        sk[i] = (i < N) ? ((rk[i] & 0xFFFFFFFF00000000ull) | (unsigned)i) : ~0ull;
    __syncthreads();
    for (unsigned k = 2; k <= 1024; k <<= 1) {
        for (unsigned j = k >> 1; j > 0; j >>= 1) {
            for (unsigned i = t; i < 1024; i += 256) {
                unsigned ixj = i ^ j;
                if (ixj > i) {
                    u64 x = sk[i], y = sk[ixj];
                    bool up = ((i & k) == 0);
                    if ((x > y) == up) { sk[i] = y; sk[ixj] = x; }
                }
            }
            __syncthreads();
        }
    }
    unsigned myidx = (unsigned)(sk[t] & 0xFFFFFFFFull);
    __syncthreads();
    unsigned* si = (unsigned*)sk;
    si[t] = myidx;
    __syncthreads();
    for (unsigned k = 2; k <= 256; k <<= 1) {
        for (unsigned j = k >> 1; j > 0; j >>= 1) {
            unsigned i = t, ixj = i ^ j;
            if (ixj > i) {
                unsigned x = si[i], y = si[ixj];
                bool up = ((i & k) == 0);
                if ((x > y) == up) { si[i] = y; si[ixj] = x; }
            }
            __syncthreads();
        }
    }
    int sel = (int)si[t];
    sel_idx[((size_t)dir * B + b) * M + t] = sel;
    nn_idx[((size_t)dir * B + b) * M + t] = (int)(unsigned)(rk[sel] & 0xFFFFFFFFull);
}

// ---------------------------------------------------------------------------
// MFMA VICReg per (pair p, location mloc), 4-chunk-resident (R6, passing).
// ---------------------------------------------------------------------------
__global__ __launch_bounds__(256, 1) void vicreg_mfma_kernel(
    const u16* __restrict__ abf, const u16* __restrict__ bbf,
    const int* __restrict__ sel_idx, const int* __restrict__ nn_idx,
    float* __restrict__ acc) {
    const int mloc = blockIdx.x;
    const int p = blockIdx.y;
    const int t = threadIdx.x;
    const int l = t & 63, w = t >> 6;

    __shared__ __align__(16) u16 Xs[4][64 * 128];   // 64 KB
    __shared__ __align__(16) u16 Ys[4][64 * 128];   // 64 KB
    __shared__ float colpart[2][4][4][128];         // [parity][wave][stat][col] 16 KB
    __shared__ float Rsx[64], Rsy[64];
    __shared__ int xi[64], yi[64];
    __shared__ float redsc[4][4];

    if (t < 64) xi[t] = sel_idx[((size_t)p * B + t) * M + mloc];
    else if (t < 128) yi[t - 64] = nn_idx[((size_t)p * B + (t - 64)) * M + mloc];
    __syncthreads();

    const u16* Xg = (p & 1) ? bbf : abf;
    const u16* Yg = (p & 1) ? abf : bbf;
    unsigned xofs[4], yofs[4];
    int ldst[4];
#pragma unroll
    for (int s = 0; s < 4; ++s) {
        int r = w * 16 + s * 4 + (l >> 4);
        int cs = (l & 15) ^ (r & 15);
        xofs[s] = (unsigned)((r * N + xi[r]) * C + cs * 8);
        yofs[s] = (unsigned)((r * N + yi[r]) * C + cs * 8);
        ldst[s] = (w * 16 + s * 4) * 128;
    }

    // ---- stage ALL 4 chunks, then drain once ----
#pragma unroll
    for (int kc = 0; kc < 4; ++kc)
#pragma unroll
        for (int s = 0; s < 4; ++s) {
            gload_lds16(Xg + xofs[s] + kc * 128, &Xs[kc][ldst[s]]);
            gload_lds16(Yg + yofs[s] + kc * 128, &Ys[kc][ldst[s]]);
        }
    __syncthreads();   // single vmcnt(0) drain: all tiles resident

    f32x4 Gx[4], Gy[4], Z;
#pragma unroll
    for (int j = 0; j < 4; ++j) { Gx[j] = (f32x4){0,0,0,0}; Gy[j] = (f32x4){0,0,0,0}; }
    Z = (f32x4){0, 0, 0, 0};
    float stdacc = 0.f, covdacc = 0.f, reprp = 0.f;

#pragma unroll
    for (int kc = 0; kc < 4; ++kc) {
        const u16* Xc = Xs[kc];
        const u16* Yc = Ys[kc];

        // ---- MFMA Grams ----
#pragma unroll
        for (int ks = 0; ks < 4; ++ks) {
            int cb = ks * 4 + (l >> 4);
            int pe = (cb ^ (l & 15)) << 3;
            short8 ax = *(const short8*)&Xc[((w << 4) + (l & 15)) * 128 + pe];
            short8 ay = *(const short8*)&Yc[((w << 4) + (l & 15)) * 128 + pe];
            short8 bx[4], by[4];
#pragma unroll
            for (int j = 0; j < 4; ++j) {
                bx[j] = *(const short8*)&Xc[(j * 16 + (l & 15)) * 128 + pe];
                by[j] = *(const short8*)&Yc[(j * 16 + (l & 15)) * 128 + pe];
            }
#pragma unroll
            for (int j = 0; j < 4; ++j) {
                Gx[j] = __builtin_amdgcn_mfma_f32_16x16x32_bf16(ax, bx[j], Gx[j], 0, 0, 0);
                Gy[j] = __builtin_amdgcn_mfma_f32_16x16x32_bf16(ay, by[j], Gy[j], 0, 0, 0);
            }
            Z = __builtin_amdgcn_mfma_f32_16x16x32_bf16(ax, ay, Z, 0, 0, 0);
        }

        // ---- column stats: per-wave partials, rows 16w..16w+15 ----
        {
            int c4 = (l & 31) << 2;
            int cc = c4 >> 3, h = (c4 >> 2) & 1;
            int g2 = (w << 1) + (l >> 5);
            float s1x0 = 0, s1x1 = 0, s1x2 = 0, s1x3 = 0;
            float s2x0 = 0, s2x1 = 0, s2x2 = 0, s2x3 = 0;
            float s1y0 = 0, s1y1 = 0, s1y2 = 0, s1y3 = 0;
            float s2y0 = 0, s2y1 = 0, s2y2 = 0, s2y3 = 0;
#pragma unroll
            for (int rr = 0; rr < 8; ++rr) {
                int r = g2 * 8 + rr;
                int off = r * 128 + ((cc ^ (r & 15)) << 3) + h * 4;
                ushort4 vx = *(const ushort4*)&Xc[off];
                ushort4 vy = *(const ushort4*)&Yc[off];
                float x0 = b2f(vx.x), x1 = b2f(vx.y), x2 = b2f(vx.z), x3 = b2f(vx.w);
                float y0 = b2f(vy.x), y1 = b2f(vy.y), y2 = b2f(vy.z), y3 = b2f(vy.w);
                s1x0 += x0; s1x1 += x1; s1x2 += x2; s1x3 += x3;
                s2x0 = fmaf(x0, x0, s2x0); s2x1 = fmaf(x1, x1, s2x1);
                s2x2 = fmaf(x2, x2, s2x2); s2x3 = fmaf(x3, x3, s2x3);
                s1y0 += y0; s1y1 += y1; s1y2 += y2; s1y3 += y3;
                s2y0 = fmaf(y0, y0, s2y0); s2y1 = fmaf(y1, y1, s2y1);
                s2y2 = fmaf(y2, y2, s2y2); s2y3 = fmaf(y3, y3, s2y3);
            }
            s1x0 += __shfl_xor(s1x0, 32, 64); s1x1 += __shfl_xor(s1x1, 32, 64);
            s1x2 += __shfl_xor(s1x2, 32, 64); s1x3 += __shfl_xor(s1x3, 32, 64);
            s2x0 += __shfl_xor(s2x0, 32, 64); s2x1 += __shfl_xor(s2x1, 32, 64);
            s2x2 += __shfl_xor(s2x2, 32, 64); s2x3 += __shfl_xor(s2x3, 32, 64);
            s1y0 += __shfl_xor(s1y0, 32, 64); s1y1 += __shfl_xor(s1y1, 32, 64);
            s1y2 += __shfl_xor(s1y2, 32, 64); s1y3 += __shfl_xor(s1y3, 32, 64);
            s2y0 += __shfl_xor(s2y0, 32, 64); s2y1 += __shfl_xor(s2y1, 32, 64);
            s2y2 += __shfl_xor(s2y2, 32, 64); s2y3 += __shfl_xor(s2y3, 32, 64);
            if (l < 32) {
                *(float4*)&colpart[kc & 1][w][0][c4] = make_float4(s1x0, s1x1, s1x2, s1x3);
                *(float4*)&colpart[kc & 1][w][1][c4] = make_float4(s2x0, s2x1, s2x2, s2x3);
                *(float4*)&colpart[kc & 1][w][2][c4] = make_float4(s1y0, s1y1, s1y2, s1y3);
                *(float4*)&colpart[kc & 1][w][3][c4] = make_float4(s2y0, s2y1, s2y2, s2y3);
            }
        }
        __syncthreads();   // stats of chunk kc visible; parity buffer isolates
                           // these reads from chunk kc+1's writes

        if (t < 128) {
            float s1x = 0, s2x = 0, s1y = 0, s2y = 0;
#pragma unroll
            for (int ww = 0; ww < 4; ++ww) {
                s1x += colpart[kc & 1][ww][0][t]; s2x += colpart[kc & 1][ww][1][t];
                s1y += colpart[kc & 1][ww][2][t]; s2y += colpart[kc & 1][ww][3][t];
            }
            float sx = s2x - s1x * s1x * (1.f / 64.f);
            float sy = s2y - s1y * s1y * (1.f / 64.f);
            stdacc += fmaxf(0.f, 1.f - sqrtf(sx * (1.f / 63.f) + 1e-4f)) +
                      fmaxf(0.f, 1.f - sqrtf(sy * (1.f / 63.f) + 1e-4f));
            covdacc += sx * sx + sy * sy;
            reprp += s2x + s2y;
        }
    }

    // ---- epilogue ----
    float zd = 0.f;
    {
        int rbase = (l >> 4) << 2, col = l & 15;
#pragma unroll
        for (int reg = 0; reg < 4; ++reg)
            zd += (col == rbase + reg) ? Z[reg] : 0.f;
    }
    float rsx[4], rsy[4];
#pragma unroll
    for (int reg = 0; reg < 4; ++reg) {
        rsx[reg] = Gx[0][reg] + Gx[1][reg] + Gx[2][reg] + Gx[3][reg];
        rsy[reg] = Gy[0][reg] + Gy[1][reg] + Gy[2][reg] + Gy[3][reg];
    }
#pragma unroll
    for (int off = 1; off < 16; off <<= 1)
#pragma unroll
        for (int reg = 0; reg < 4; ++reg) {
            rsx[reg] += __shfl_xor(rsx[reg], off, 64);
            rsy[reg] += __shfl_xor(rsy[reg], off, 64);
        }
    if ((l & 15) == 0) {
#pragma unroll
        for (int reg = 0; reg < 4; ++reg) {
            Rsx[(w << 4) + ((l >> 4) << 2) + reg] = rsx[reg];
            Rsy[(w << 4) + ((l >> 4) << 2) + reg] = rsy[reg];
        }
    }
    __syncthreads();
    float myx = Rsx[l], myy = Rsy[l];
#pragma unroll
    for (int off = 1; off < 64; off <<= 1) {
        myx += __shfl_xor(myx, off, 64);
        myy += __shfl_xor(myy, off, 64);
    }
    float tX = myx * (1.f / 4096.f), tY = myy * (1.f / 4096.f);
    float kn = 0.f;
#pragma unroll
    for (int j = 0; j < 4; ++j) {
        float cX = Rsx[(j << 4) + (l & 15)] * (1.f / 64.f);
        float cY = Rsy[(j << 4) + (l & 15)] * (1.f / 64.f);
#pragma unroll
        for (int reg = 0; reg < 4; ++reg) {
            float K1 = Gx[j][reg] - rsx[reg] * (1.f / 64.f) - cX + tX;
            kn = fmaf(K1, K1, kn);
            float K2 = Gy[j][reg] - rsy[reg] * (1.f / 64.f) - cY + tY;
            kn = fmaf(K2, K2, kn);
        }
    }

    float v0 = reprp - 2.f * zd, v1 = stdacc, v2 = covdacc, v3 = kn;
#pragma unroll
    for (int off = 1; off < 64; off <<= 1) {
        v0 += __shfl_xor(v0, off, 64);
        v1 += __shfl_xor(v1, off, 64);
        v2 += __shfl_xor(v2, off, 64);
        v3 += __shfl_xor(v3, off, 64);
    }
    if (l == 0) { redsc[w][0] = v0; redsc[w][1] = v1; redsc[w][2] = v2; redsc[w][3] = v3; }
    __syncthreads();
    if (t == 0) {
        float r0 = 0, r1 = 0, r2 = 0, r3 = 0;
#pragma unroll
        for (int ww = 0; ww < 4; ++ww) {
            r0 += redsc[ww][0]; r1 += redsc[ww][1];
            r2 += redsc[ww][2]; r3 += redsc[ww][3];
        }
        atomicAdd(&acc[0], r0);
        atomicAdd(&acc[1], r1);
        atomicAdd(&acc[2], r3 - r2);
    }
}

// ---------------------------------------------------------------------------
// FALLBACK fp32 path kernels (only if ws can't hold bf16 copies)
// ---------------------------------------------------------------------------
__global__ __launch_bounds__(256) void norms_kernel(const float* __restrict__ m1,
                                                    const float* __restrict__ m2,
                                                    float* __restrict__ nrm) {
    int w = blockIdx.x * 4 + (threadIdx.x >> 6);
    int lane = threadIdx.x & 63;
    if (w >= 2 * B * N) return;
    const float* src = (w < B * N) ? m1 : m2;
    int row = (w < B * N) ? w : w - B * N;
    const float4* p = (const float4*)(src + (size_t)row * C);
    float s = 0.f;
#pragma unroll
    for (int i = 0; i < 2; ++i) {
        float4 v = p[lane + i * 64];
        s += v.x * v.x + v.y * v.y + v.z * v.z + v.w * v.w;
    }
#pragma unroll
    for (int off = 32; off > 0; off >>= 1) s += __shfl_down(s, off, 64);
    if (lane == 0) nrm[w] = s;
}

__global__ __launch_bounds__(256) void feat_dist_kernel(
    const float* __restrict__ m1, const float* __restrict__ m2,
    const float* __restrict__ nrm, u64* __restrict__ rowkey) {
    const int b = blockIdx.z;
    const int tn = blockIdx.x, tm = blockIdx.y;
    __shared__ float As[64][68];
    __shared__ float Bt[64][68];
    __shared__ u64 red[64][16];
    const int t = threadIdx.x;
    const int ty = t >> 4, tx = t & 15;
    float acc[4][4] = {};
    const float* A = m1 + (size_t)b * N * C;
    const float* Bm = m2 + (size_t)b * N * C;

    for (int k0 = 0; k0 < C; k0 += 64) {
#pragma unroll
        for (int it = 0; it < 4; ++it) {
            int idx = t + it * 256;
            int r = idx >> 4, cc = (idx & 15) << 2;
            int n = tn * 64 + r;
            float4 v = make_float4(0.f, 0.f, 0.f, 0.f);
            if (n < N) v = *(const float4*)(A + (size_t)n * C + k0 + cc);
            *(float4*)&As[r][cc] = v;
            int mm = tm * 64 + r;
            float4 w = make_float4(0.f, 0.f, 0.f, 0.f);
            if (mm < N) w = *(const float4*)(Bm + (size_t)mm * C + k0 + cc);
            Bt[cc + 0][r] = w.x; Bt[cc + 1][r] = w.y;
            Bt[cc + 2][r] = w.z; Bt[cc + 3][r] = w.w;
        }
        __syncthreads();
#pragma unroll 4
        for (int kq = 0; kq < 64; kq += 4) {
            float aa[4][4], bb[4][4];
#pragma unroll
            for (int i = 0; i < 4; ++i) {
                float4 v = *(const float4*)&As[ty * 4 + i][kq];
                aa[i][0] = v.x; aa[i][1] = v.y; aa[i][2] = v.z; aa[i][3] = v.w;
            }
#pragma unroll
            for (int qq = 0; qq < 4; ++qq) {
                float4 v = *(const float4*)&Bt[kq + qq][tx * 4];
                bb[qq][0] = v.x; bb[qq][1] = v.y; bb[qq][2] = v.z; bb[qq][3] = v.w;
            }
#pragma unroll
            for (int qq = 0; qq < 4; ++qq)
#pragma unroll
                for (int i = 0; i < 4; ++i)
#pragma unroll
                    for (int j = 0; j < 4; ++j)
                        acc[i][j] = fmaf(aa[i][qq], bb[qq][j], acc[i][j]);
        }
        __syncthreads();
    }

    u64 rk[4] = {~0ull, ~0ull, ~0ull, ~0ull};
    u64 ck[4] = {~0ull, ~0ull, ~0ull, ~0ull};
    const float* nr1 = nrm;
    const float* nr2 = nrm + B * N;
#pragma unroll
    for (int i = 0; i < 4; ++i) {
        int n = tn * 64 + ty * 4 + i;
        if (n >= N) continue;
        float a2 = nr1[b * N + n];
#pragma unroll
        for (int j = 0; j < 4; ++j) {
            int mm = tm * 64 + tx * 4 + j;
            if (mm >= N) continue;
            float b2 = nr2[b * N + mm];
            float d2 = a2 + b2 - 2.f * acc[i][j];
            unsigned vb = __float_as_uint(fmaxf(d2, 0.f));
            u64 kv = ((u64)vb << 32);
            rk[i] = umin64(rk[i], kv | (unsigned)mm);
            ck[j] = umin64(ck[j], kv | (unsigned)n);
        }
    }
#pragma unroll
    for (int i = 0; i < 4; ++i) red[ty * 4 + i][tx] = rk[i];
    __syncthreads();
    if (t < 64) {
        u64 best = red[t][0];
#pragma unroll
        for (int x = 1; x < 16; ++x) best = umin64(best, red[t][x]);
        int n = tn * 64 + t;
        if (n < N && best != ~0ull)
            atomicMin(&rowkey[(size_t)b * N + n], best);
    }
    __syncthreads();
#pragma unroll
    for (int j = 0; j < 4; ++j) red[tx * 4 + j][ty] = ck[j];
    __syncthreads();
    if (t < 64) {
        u64 best = red[t][0];
#pragma unroll
        for (int x = 1; x < 16; ++x) best = umin64(best, red[t][x]);
        int mm = tm * 64 + t;
        if (mm < N && best != ~0ull)
            atomicMin(&rowkey[(size_t)B * N + (size_t)b * N + mm], best);
    }
}

__device__ __forceinline__ float blockReduce(float v, float* redb, int t) {
    __syncthreads();
    redb[t] = v;
    __syncthreads();
    for (int s = 128; s > 0; s >>= 1) {
        if (t < s) redb[t] += redb[t + s];
        __syncthreads();
    }
    return redb[0];
}

__global__ __launch_bounds__(256) void vicreg_kernel(
    const float* __restrict__ m1, const float* __restrict__ m2,
    const int* __restrict__ sel_idx, const int* __restrict__ nn_idx,
    float* __restrict__ acc) {
    const int mloc = blockIdx.x;
    const int p = blockIdx.y;
    const int t = threadIdx.x;
    const float* X = (p & 1) ? m2 : m1;
    const float* Y = (p & 1) ? m1 : m2;
    __shared__ float Xs[64][65];
    __shared__ float Ys[64][65];
    __shared__ int xi[64], yi[64];
    __shared__ float pst[192][5];
    __shared__ float Rs[64];
    __shared__ float Tsh;
    __shared__ float redb[256];

    if (t < 64) {
        xi[t] = sel_idx[((size_t)p * B + t) * M + mloc];
        yi[t] = nn_idx[((size_t)p * B + t) * M + mloc];
    }
    __syncthreads();

    float Gx[4][4] = {}, Gy[4][4] = {};
    float stdx = 0, stdy = 0, covdx = 0, covdy = 0, repr = 0;
    const int i0 = (t >> 4) << 2, j0 = (t & 15) << 2;

    for (int c0 = 0; c0 < C; c0 += 64) {
#pragma unroll
        for (int it = 0; it < 4; ++it) {
            int fidx = t + it * 256;
            int r = fidx >> 4, cc = (fidx & 15) << 2;
            float4 v = *(const float4*)(X + ((size_t)r * N + xi[r]) * C + c0 + cc);
            Xs[r][cc] = v.x; Xs[r][cc + 1] = v.y; Xs[r][cc + 2] = v.z; Xs[r][cc + 3] = v.w;
            float4 w = *(const float4*)(Y + ((size_t)r * N + yi[r]) * C + c0 + cc);
            Ys[r][cc] = w.x; Ys[r][cc + 1] = w.y; Ys[r][cc + 2] = w.z; Ys[r][cc + 3] = w.w;
        }
        __syncthreads();
#pragma unroll 4
        for (int k = 0; k < 64; ++k) {
            float ax[4], bx[4], ay[4], by[4];
#pragma unroll
            for (int i = 0; i < 4; ++i) { ax[i] = Xs[i0 + i][k]; ay[i] = Ys[i0 + i][k]; }
#pragma unroll
            for (int j = 0; j < 4; ++j) { bx[j] = Xs[j0 + j][k]; by[j] = Ys[j0 + j][k]; }
#pragma unroll
            for (int i = 0; i < 4; ++i)
#pragma unroll
                for (int j = 0; j < 4; ++j) {
                    Gx[i][j] = fmaf(ax[i], bx[j], Gx[i][j]);
                    Gy[i][j] = fmaf(ay[i], by[j], Gy[i][j]);
                }
        }
        {
            float s1x = 0, s2x = 0, s1y = 0, s2y = 0, sxy = 0;
            int col = t & 63, g = t >> 6;
            for (int r = g * 16; r < g * 16 + 16; ++r) {
                float xv = Xs[r][col], yv = Ys[r][col];
                s1x += xv; s2x += xv * xv;
                s1y += yv; s2y += yv * yv;
                sxy += xv * yv;
            }
            if (g) {
                float* qq = pst[(g - 1) * 64 + col];
                qq[0] = s1x; qq[1] = s2x; qq[2] = s1y; qq[3] = s2y; qq[4] = sxy;
            }
            __syncthreads();
            if (g == 0) {
#pragma unroll
                for (int gg = 0; gg < 3; ++gg) {
                    float* qq = pst[gg * 64 + col];
                    s1x += qq[0]; s2x += qq[1]; s1y += qq[2]; s2y += qq[3]; sxy += qq[4];
                }
                float xb = s1x * (1.f / 64.f);
                float sx = s2x - 64.f * xb * xb;
                float yb = s1y * (1.f / 64.f);
                float sy = s2y - 64.f * yb * yb;
                stdx += fmaxf(0.f, 1.f - sqrtf(sx * (1.f / 63.f) + 1e-4f));
                stdy += fmaxf(0.f, 1.f - sqrtf(sy * (1.f / 63.f) + 1e-4f));
                covdx += sx * sx;
                covdy += sy * sy;
                repr += s2x + s2y - 2.f * sxy;
            }
            __syncthreads();
        }
    }

    float knx = 0.f, kny = 0.f;
    float (*Gs)[65] = (float(*)[65]) & Xs[0][0];
    __syncthreads();
#pragma unroll
    for (int i = 0; i < 4; ++i)
#pragma unroll
        for (int j = 0; j < 4; ++j) Gs[i0 + i][j0 + j] = Gx[i][j];
    __syncthreads();
    if (t < 64) {
        float r = 0;
        for (int j = 0; j < 64; ++j) r += Gs[t][j];
        Rs[t] = r;
    }
    __syncthreads();
    if (t < 64) {
        float r = Rs[t];
#pragma unroll
        for (int off = 32; off > 0; off >>= 1) r += __shfl_down(r, off, 64);
        if (t == 0) Tsh = r;
    }
    __syncthreads();
    {
        float T = Tsh * (1.f / 4096.f);
#pragma unroll
        for (int i = 0; i < 4; ++i)
#pragma unroll
            for (int j = 0; j < 4; ++j) {
                float Kij = Gx[i][j] - (Rs[i0 + i] + Rs[j0 + j]) * (1.f / 64.f) + T;
                knx = fmaf(Kij, Kij, knx);
            }
    }
    __syncthreads();
#pragma unroll
    for (int i = 0; i < 4; ++i)
#pragma unroll
        for (int j = 0; j < 4; ++j) Gs[i0 + i][j0 + j] = Gy[i][j];
    __syncthreads();
    if (t < 64) {
        float r = 0;
        for (int j = 0; j < 64; ++j) r += Gs[t][j];
        Rs[t] = r;
    }
    __syncthreads();
    if (t < 64) {
        float r = Rs[t];
#pragma unroll
        for (int off = 32; off > 0; off >>= 1) r += __shfl_down(r, off, 64);
        if (t == 0) Tsh = r;
    }
    __syncthreads();
    {
        float T = Tsh * (1.f / 4096.f);
#pragma unroll
        for (int i = 0; i < 4; ++i)
#pragma unroll
            for (int j = 0; j < 4; ++j) {
                float Kij = Gy[i][j] - (Rs[i0 + i] + Rs[j0 + j]) * (1.f / 64.f) + T;
                kny = fmaf(Kij, Kij, kny);
            }
    }

    float v_repr = blockReduce(repr, redb, t);
    float v_std = blockReduce(stdx + stdy, redb, t);
    float v_covd = blockReduce(covdx + covdy, redb, t);
    float v_kn = blockReduce(knx + kny, redb, t);
    if (t == 0) {
        atomicAdd(&acc[0], v_repr);
        atomicAdd(&acc[1], v_std);
        atomicAdd(&acc[2], v_kn - v_covd);
    }
}

// ---------------------------------------------------------------------------
__global__ void finalize_kernel(const float* __restrict__ acc, float* __restrict__ out) {
    if (threadIdx.x == 0 && blockIdx.x == 0) {
        float repr = 25.f * acc[0] / ((float)B * (float)M * (float)C);
        float stdl = 12.5f * acc[1] / ((float)M * (float)C);
        float cov = acc[2] / (63.f * 63.f * (float)C * 2.f) / (float)M;
        out[0] = repr + stdl + cov;
    }
}

// ---------------------------------------------------------------------------
extern "C" void kernel_launch(void* const* d_in, const int* in_sizes, int n_in,
                              void* d_out, int out_size, void* d_ws, size_t ws_size,
                              hipStream_t stream) {
    const float* m1 = (const float*)d_in[0];
    const float* m2 = (const float*)d_in[1];
    const float* l1 = (const float*)d_in[2];
    const float* l2 = (const float*)d_in[3];
    float* out = (float*)d_out;
    char* ws = (char*)d_ws;

    u64* rowkey = (u64*)ws;                                   // [4][B][N]
    size_t off = (size_t)4 * B * N * sizeof(u64);
    float* nrm = (float*)(ws + off); off += (size_t)2 * B * N * sizeof(float);
    int* sel_idx = (int*)(ws + off); off += (size_t)4 * B * M * sizeof(int);
    int* nn_idx = (int*)(ws + off);  off += (size_t)4 * B * M * sizeof(int);
    float* acc = (float*)(ws + off); off += 256;
    off = (off + 255) & ~(size_t)255;
    u16* abf = (u16*)(ws + off);
    u16* bbf = abf + (size_t)B * N * C;
    size_t need = off + (size_t)2 * B * N * C * sizeof(u16);
    bool use_mfma = ws_size >= need;          // ws_size fixed -> deterministic

    // ws is NOT re-poisoned between replays: re-init everything we read.
    // Only dirs 0,1 need ~0 keys (feat uses atomicMin); loc_dist plain-stores
    // dirs 2,3; acc is zeroed by select_kernel (runs before vicreg).
    hipMemsetAsync(rowkey, 0xFF, (size_t)2 * B * N * sizeof(u64), stream);
    if (use_mfma) {
        convnorm_kernel<<<dim3(2 * B * N / 4), dim3(256), 0, stream>>>(m1, m2, abf, bbf, nrm);
        feat_mfma_kernel<<<dim3(64 * 49), dim3(256), 0, stream>>>(abf, bbf, nrm, rowkey);
    } else {
        norms_kernel<<<dim3(2 * B * N / 4), dim3(256), 0, stream>>>(m1, m2, nrm);
        feat_dist_kernel<<<dim3(13, 13, B), dim3(256), 0, stream>>>(m1, m2, nrm, rowkey);
    }
    loc_dist_kernel<<<dim3((N + 255) / 256, B, 2), dim3(256), 0, stream>>>(l1, l2, rowkey);
    select_kernel<<<dim3(B, 4), dim3(256), 0, stream>>>(rowkey, sel_idx, nn_idx, acc);
    if (use_mfma) {
        vicreg_mfma_kernel<<<dim3(M, 4), dim3(256), 0, stream>>>(abf, bbf, sel_idx, nn_idx, acc);
    } else {
        vicreg_kernel<<<dim3(M, 4), dim3(256), 0, stream>>>(m1, m2, sel_idx, nn_idx, acc);
    }
    finalize_kernel<<<dim3(1), dim3(64), 0, stream>>>(acc, out);
}